// Round 2
// baseline (369.931 us; speedup 1.0000x reference)
//
#include <hip/hip_runtime.h>
#include <stdint.h>

typedef unsigned short u16;
typedef unsigned int u32;
typedef __attribute__((ext_vector_type(8))) short short8;
typedef __attribute__((ext_vector_type(4))) float f32x4;
typedef __attribute__((ext_vector_type(4))) unsigned short u16x4;

#define LDS_AS __attribute__((address_space(3)))
#define GLB_AS __attribute__((address_space(1)))

__device__ __forceinline__ u16 f2bf(float f) {
  u32 u = __float_as_uint(f);
  u = (u + 0x7FFFu + ((u >> 16) & 1u)) >> 16;
  return (u16)u;
}

__device__ __forceinline__ void gload_lds16(const u16* g, u16* l) {
  __builtin_amdgcn_global_load_lds((const GLB_AS u32*)g, (LDS_AS u32*)l, 16, 0, 0);
}

__device__ __forceinline__ f32x4 mfma16(short8 a, short8 b, f32x4 c) {
  return __builtin_amdgcn_mfma_f32_16x16x32_bf16(a, b, c, 0, 0, 0);
}

// ---------------- fp32 -> bf16 elementwise convert (vectorized) ----------------
__global__ __launch_bounds__(256) void k_cvt(const float* __restrict__ in,
                                             u16* __restrict__ out, int n4) {
  int i = blockIdx.x * 256 + threadIdx.x;
  if (i >= n4) return;
  f32x4 v = ((const f32x4*)in)[i];
  u16x4 o = {f2bf(v[0]), f2bf(v[1]), f2bf(v[2]), f2bf(v[3])};
  ((u16x4*)out)[i] = o;
}

// ---------------- W [K][N] f32 -> Wt [N][K] bf16 (LDS tile transpose) ----------------
__global__ __launch_bounds__(256) void k_transpose_cvt(const float* __restrict__ W,
                                                       u16* __restrict__ Wt, int K, int N) {
  __shared__ float tile[32][33];
  int n0 = blockIdx.x * 32;
  int k0 = blockIdx.y * 32;
  int tx = threadIdx.x & 31, ty = threadIdx.x >> 5;  // ty 0..7
#pragma unroll
  for (int i = 0; i < 4; i++) {
    int k = k0 + ty + i * 8;
    tile[ty + i * 8][tx] = W[(size_t)k * N + n0 + tx];
  }
  __syncthreads();
#pragma unroll
  for (int i = 0; i < 4; i++) {
    int n = n0 + ty + i * 8;
    Wt[(size_t)n * K + k0 + tx] = f2bf(tile[tx][ty + i * 8]);
  }
}

// ---------------- bf16 GEMM: C[M][N] = A[M][K] * Bt[N][K]^T + bias ----------------
template <bool OUT_BF16>
__global__ __launch_bounds__(256) void k_gemm(const u16* __restrict__ A,
                                              const u16* __restrict__ Bt,
                                              const float* __restrict__ bias,
                                              void* __restrict__ C, int M, int N, int K) {
  __shared__ u16 As[128 * 32];
  __shared__ u16 Bs[128 * 32];
  const int nwg = gridDim.x;
  const int wgo = blockIdx.x;
  const int cpx = nwg >> 3;  // grids are multiples of 8
  const int swz = (wgo & 7) * cpx + (wgo >> 3);
  const int ntn = N >> 7;
  const int tm = swz / ntn, tn = swz % ntn;
  const int m0 = tm << 7, n0 = tn << 7;
  const int tid = threadIdx.x;
  const int lane = tid & 63, w = tid >> 6;
  const int wm = (w >> 1) << 6, wn = (w & 1) << 6;
  const int fr = lane & 15, kb = (lane >> 4) << 3;

  f32x4 acc[4][4];
#pragma unroll
  for (int i = 0; i < 4; i++)
#pragma unroll
    for (int j = 0; j < 4; j++) acc[i][j] = (f32x4){0.f, 0.f, 0.f, 0.f};

  const int ldr = tid >> 2;
  const int ldc = (tid & 3) << 3;
  const u16* ga = A + (size_t)(m0 + ldr) * K + ldc;
  const u16* gb = Bt + (size_t)(n0 + ldr) * K + ldc;
  u16* lA0 = &As[tid * 8];
  u16* lA1 = &As[2048 + tid * 8];
  u16* lB0 = &Bs[tid * 8];
  u16* lB1 = &Bs[2048 + tid * 8];
  const size_t rows64 = (size_t)64 * K;

  for (int k0 = 0; k0 < K; k0 += 32) {
    __syncthreads();
    gload_lds16(ga + k0, lA0);
    gload_lds16(ga + k0 + rows64, lA1);
    gload_lds16(gb + k0, lB0);
    gload_lds16(gb + k0 + rows64, lB1);
    __syncthreads();
    short8 af[4], bf[4];
#pragma unroll
    for (int mi = 0; mi < 4; mi++)
      af[mi] = *(const short8*)&As[(wm + mi * 16 + fr) * 32 + kb];
#pragma unroll
    for (int nj = 0; nj < 4; nj++)
      bf[nj] = *(const short8*)&Bs[(wn + nj * 16 + fr) * 32 + kb];
#pragma unroll
    for (int mi = 0; mi < 4; mi++)
#pragma unroll
      for (int nj = 0; nj < 4; nj++)
        acc[mi][nj] = mfma16(af[mi], bf[nj], acc[mi][nj]);
  }

  const int r0 = (lane >> 4) << 2;
#pragma unroll
  for (int mi = 0; mi < 4; mi++) {
    const int row = m0 + wm + mi * 16 + r0;
#pragma unroll
    for (int nj = 0; nj < 4; nj++) {
      const int col = n0 + wn + nj * 16 + fr;
      const float bs = bias[col];
      f32x4 v = acc[mi][nj];
#pragma unroll
      for (int r = 0; r < 4; r++) {
        float val = v[r] + bs;
        if (OUT_BF16)
          ((u16*)C)[(size_t)(row + r) * N + col] = f2bf(val);
        else
          ((float*)C)[(size_t)(row + r) * N + col] = val;
      }
    }
  }
}

// ---------------- flash attention: qkv[16384][2304] bf16 -> y[16384][768] bf16 ----------------
__global__ __launch_bounds__(256) void k_attn(const u16* __restrict__ qkv,
                                              const int* __restrict__ amask,
                                              u16* __restrict__ y) {
  __shared__ u16 Qs[64 * 64];
  __shared__ u16 Ks[64 * 64];
  __shared__ u16 Vt[64 * 72];
  __shared__ u16 Ps[4 * 16 * 72];

  const int qt = blockIdx.x;   // 0..15
  const int bh = blockIdx.y;   // 0..191
  const int b = bh / 12, h = bh % 12;
  const int qbase = qt * 64;
  const int tid = threadIdx.x;
  const int lane = tid & 63;
  const int w = tid >> 6;
  const int fr = lane & 15;
  const int kg = lane >> 4;
  const int srow = tid >> 3;  // 0..31
  const int scb = tid & 7;

  const size_t basebt = (size_t)b * 1024 * 2304;
  const u16* qg = qkv + basebt + (size_t)qbase * 2304 + h * 64;
  const u16* kgb = qkv + basebt + 768 + h * 64;
  const u16* vgb = qkv + basebt + 1536 + h * 64;
  const int* mrow = amask + b * 1024;

  // stage Q once (XOR-swizzled via pre-swizzled global source)
  {
    int r0 = srow, r1 = srow + 32;
    gload_lds16(qg + (size_t)r0 * 2304 + ((scb ^ (r0 & 7)) << 3), &Qs[tid * 8]);
    gload_lds16(qg + (size_t)r1 * 2304 + ((scb ^ (r1 & 7)) << 3), &Qs[2048 + tid * 8]);
  }
  __syncthreads();

  short8 qf[2];
  {
    int row = w * 16 + fr;
    int p0 = (kg ^ (row & 7)) << 3;
    int p1 = ((kg + 4) ^ (row & 7)) << 3;
    qf[0] = *(const short8*)&Qs[row * 64 + p0];
    qf[1] = *(const short8*)&Qs[row * 64 + p1];
  }

  f32x4 oacc[4];
  float mrun[4], lrun[4];
#pragma unroll
  for (int i = 0; i < 4; i++) {
    oacc[i] = (f32x4){0.f, 0.f, 0.f, 0.f};
    mrun[i] = -1e30f;
    lrun[i] = 0.f;
  }

  u16* Pw = &Ps[w * 16 * 72];

  for (int kv0 = 0; kv0 <= qbase; kv0 += 64) {
    __syncthreads();
    // stage K (swizzled, direct-to-LDS)
    {
      int r0 = srow, r1 = srow + 32;
      gload_lds16(kgb + (size_t)(kv0 + r0) * 2304 + ((scb ^ (r0 & 7)) << 3), &Ks[tid * 8]);
      gload_lds16(kgb + (size_t)(kv0 + r1) * 2304 + ((scb ^ (r1 & 7)) << 3),
                  &Ks[2048 + tid * 8]);
    }
    // stage V transposed (register path, padded rows)
#pragma unroll
    for (int j = 0; j < 2; j++) {
      int t = j * 32 + srow;
      short8 vv = *(const short8*)(vgb + (size_t)(kv0 + t) * 2304 + (scb << 3));
#pragma unroll
      for (int e = 0; e < 8; e++) Vt[(scb * 8 + e) * 72 + t] = (u16)vv[e];
    }
    __syncthreads();

    // S = Q K^T (per wave: 16 q rows x 64 kv)
    f32x4 sacc[4];
#pragma unroll
    for (int nf = 0; nf < 4; nf++) sacc[nf] = (f32x4){0.f, 0.f, 0.f, 0.f};
#pragma unroll
    for (int nf = 0; nf < 4; nf++) {
      int krow = nf * 16 + fr;
      int p0 = (kg ^ (krow & 7)) << 3;
      int p1 = ((kg + 4) ^ (krow & 7)) << 3;
      short8 kf0 = *(const short8*)&Ks[krow * 64 + p0];
      short8 kf1 = *(const short8*)&Ks[krow * 64 + p1];
      sacc[nf] = mfma16(qf[0], kf0, sacc[nf]);
      sacc[nf] = mfma16(qf[1], kf1, sacc[nf]);
    }

    // scale + causal/key mask + online softmax
    float p[4][4];
    float mloc[4] = {-1e30f, -1e30f, -1e30f, -1e30f};
#pragma unroll
    for (int nf = 0; nf < 4; nf++) {
      int kv = kv0 + nf * 16 + fr;
      bool km = (mrow[kv] != 0);
#pragma unroll
      for (int r = 0; r < 4; r++) {
        int q = qbase + w * 16 + kg * 4 + r;
        float v = sacc[nf][r] * 0.125f;
        if (kv > q || !km) v = -1e9f;
        p[nf][r] = v;
        mloc[r] = fmaxf(mloc[r], v);
      }
    }
    float alpha[4];
#pragma unroll
    for (int r = 0; r < 4; r++) {
      float m = mloc[r];
      m = fmaxf(m, __shfl_xor(m, 1));
      m = fmaxf(m, __shfl_xor(m, 2));
      m = fmaxf(m, __shfl_xor(m, 4));
      m = fmaxf(m, __shfl_xor(m, 8));
      float mnew = fmaxf(mrun[r], m);
      alpha[r] = __expf(mrun[r] - mnew);
      mrun[r] = mnew;
    }
    float psum[4] = {0.f, 0.f, 0.f, 0.f};
#pragma unroll
    for (int nf = 0; nf < 4; nf++)
#pragma unroll
      for (int r = 0; r < 4; r++) {
        float e = __expf(p[nf][r] - mrun[r]);
        p[nf][r] = e;
        psum[r] += e;
      }
#pragma unroll
    for (int r = 0; r < 4; r++) {
      float s = psum[r];
      s += __shfl_xor(s, 1);
      s += __shfl_xor(s, 2);
      s += __shfl_xor(s, 4);
      s += __shfl_xor(s, 8);
      lrun[r] = lrun[r] * alpha[r] + s;
#pragma unroll
      for (int df = 0; df < 4; df++) oacc[df][r] *= alpha[r];
    }
    // P -> bf16 -> per-wave LDS (A-fragment layout round trip)
#pragma unroll
    for (int nf = 0; nf < 4; nf++)
#pragma unroll
      for (int r = 0; r < 4; r++)
        Pw[(kg * 4 + r) * 72 + nf * 16 + fr] = f2bf(p[nf][r]);

    // O += P V
#pragma unroll
    for (int kc = 0; kc < 2; kc++) {
      short8 pf = *(const short8*)&Pw[fr * 72 + kc * 32 + kg * 8];
#pragma unroll
      for (int df = 0; df < 4; df++) {
        short8 vf = *(const short8*)&Vt[(df * 16 + fr) * 72 + kc * 32 + kg * 8];
        oacc[df] = mfma16(pf, vf, oacc[df]);
      }
    }
  }

  // epilogue: normalize, query mask, write y bf16 in [token][C] layout
#pragma unroll
  for (int r = 0; r < 4; r++) {
    int q = qbase + w * 16 + kg * 4 + r;
    float inv = 1.f / lrun[r];
    float qm = (mrow[q] != 0) ? 1.f : 0.f;
#pragma unroll
    for (int df = 0; df < 4; df++) {
      float val = oacc[df][r] * inv * qm;
      y[(size_t)(b * 1024 + q) * 768 + h * 64 + df * 16 + fr] = f2bf(val);
    }
  }
}

extern "C" void kernel_launch(void* const* d_in, const int* in_sizes, int n_in,
                              void* d_out, int out_size, void* d_ws, size_t ws_size,
                              hipStream_t stream) {
  const float* x = (const float*)d_in[0];
  const int* amask = (const int*)d_in[1];
  const float* W_attn = (const float*)d_in[2];
  const float* b_attn = (const float*)d_in[3];
  const float* W_proj = (const float*)d_in[4];
  const float* b_proj = (const float*)d_in[5];
  float* out = (float*)d_out;

  // workspace layout (bf16 halves), ~131 MB total
  u16* xb = (u16*)d_ws;                          // 16384*768
  u16* wta = xb + (size_t)16384 * 768;           // 2304*768
  u16* wtp = wta + (size_t)2304 * 768;           // 768*768
  u16* qkv = wtp + (size_t)768 * 768;            // 16384*2304
  u16* yb = qkv + (size_t)16384 * 2304;          // 16384*768

  (void)in_sizes; (void)n_in; (void)out_size; (void)ws_size;

  k_cvt<<<(16384 * 768 / 4) / 256, 256, 0, stream>>>(x, xb, 16384 * 768 / 4);
  k_transpose_cvt<<<dim3(2304 / 32, 768 / 32), 256, 0, stream>>>(W_attn, wta, 768, 2304);
  k_transpose_cvt<<<dim3(768 / 32, 768 / 32), 256, 0, stream>>>(W_proj, wtp, 768, 768);

  k_gemm<true><<<(16384 / 128) * (2304 / 128), 256, 0, stream>>>(xb, wta, b_attn, qkv,
                                                                 16384, 2304, 768);
  k_attn<<<dim3(16, 192), 256, 0, stream>>>(qkv, amask, yb);
  k_gemm<false><<<(16384 / 128) * (768 / 128), 256, 0, stream>>>(yb, wtp, b_proj, out,
                                                                 16384, 768, 768);
}

// Round 3
// 263.942 us; speedup vs baseline: 1.4016x; 1.4016x over previous
//
#include <hip/hip_runtime.h>
#include <stdint.h>

typedef unsigned short u16;
typedef unsigned int u32;
typedef __attribute__((ext_vector_type(8))) short short8;
typedef __attribute__((ext_vector_type(4))) float f32x4;
typedef __attribute__((ext_vector_type(4))) unsigned short u16x4;

#define LDS_AS __attribute__((address_space(3)))
#define GLB_AS __attribute__((address_space(1)))

__device__ __forceinline__ u16 f2bf(float f) {
  u32 u = __float_as_uint(f);
  u = (u + 0x7FFFu + ((u >> 16) & 1u)) >> 16;
  return (u16)u;
}

__device__ __forceinline__ void gload_lds16(const u16* g, u16* l) {
  __builtin_amdgcn_global_load_lds((const GLB_AS u32*)g, (LDS_AS u32*)l, 16, 0, 0);
}

__device__ __forceinline__ f32x4 mfma16(short8 a, short8 b, f32x4 c) {
  return __builtin_amdgcn_mfma_f32_16x16x32_bf16(a, b, c, 0, 0, 0);
}

// ---------------- fp32 -> bf16 elementwise convert (vectorized) ----------------
__global__ __launch_bounds__(256) void k_cvt(const float* __restrict__ in,
                                             u16* __restrict__ out, int n4) {
  int i = blockIdx.x * 256 + threadIdx.x;
  if (i >= n4) return;
  f32x4 v = ((const f32x4*)in)[i];
  u16x4 o = {f2bf(v[0]), f2bf(v[1]), f2bf(v[2]), f2bf(v[3])};
  ((u16x4*)out)[i] = o;
}

// ---------------- W [K][N] f32 -> Wt [N][K] bf16 (LDS tile transpose) ----------------
__global__ __launch_bounds__(256) void k_transpose_cvt(const float* __restrict__ W,
                                                       u16* __restrict__ Wt, int K, int N) {
  __shared__ float tile[32][33];
  int n0 = blockIdx.x * 32;
  int k0 = blockIdx.y * 32;
  int tx = threadIdx.x & 31, ty = threadIdx.x >> 5;  // ty 0..7
#pragma unroll
  for (int i = 0; i < 4; i++) {
    int k = k0 + ty + i * 8;
    tile[ty + i * 8][tx] = W[(size_t)k * N + n0 + tx];
  }
  __syncthreads();
#pragma unroll
  for (int i = 0; i < 4; i++) {
    int n = n0 + ty + i * 8;
    Wt[(size_t)n * K + k0 + tx] = f2bf(tile[tx][ty + i * 8]);
  }
}

// ---------------- bf16 GEMM: C = A[M][K] * Bt[N][K]^T + bias ----------------
// MODE 0: fp32 C[M][N].  MODE 1: qkv split -> qk bf16 [M][1536] (cols<1536) and
// vT bf16 [B*H][64][1024] (cols>=1536, transposed per head).
template <int MODE>
__global__ __launch_bounds__(256) void k_gemm(const u16* __restrict__ A,
                                              const u16* __restrict__ Bt,
                                              const float* __restrict__ bias,
                                              void* __restrict__ C, u16* __restrict__ vTo,
                                              int M, int N, int K) {
  __shared__ u16 As[128 * 32];
  __shared__ u16 Bs[128 * 32];
  const int nwg = gridDim.x;
  const int wgo = blockIdx.x;
  const int cpx = nwg >> 3;  // grids are multiples of 8
  const int swz = (wgo & 7) * cpx + (wgo >> 3);
  const int ntn = N >> 7;
  const int tm = swz / ntn, tn = swz % ntn;
  const int m0 = tm << 7, n0 = tn << 7;
  const int tid = threadIdx.x;
  const int lane = tid & 63, w = tid >> 6;
  const int wm = (w >> 1) << 6, wn = (w & 1) << 6;
  const int fr = lane & 15, kb = (lane >> 4) << 3;

  f32x4 acc[4][4];
#pragma unroll
  for (int i = 0; i < 4; i++)
#pragma unroll
    for (int j = 0; j < 4; j++) acc[i][j] = (f32x4){0.f, 0.f, 0.f, 0.f};

  const int ldr = tid >> 2;
  const int ldc = (tid & 3) << 3;
  const u16* ga = A + (size_t)(m0 + ldr) * K + ldc;
  const u16* gb = Bt + (size_t)(n0 + ldr) * K + ldc;
  u16* lA0 = &As[tid * 8];
  u16* lA1 = &As[2048 + tid * 8];
  u16* lB0 = &Bs[tid * 8];
  u16* lB1 = &Bs[2048 + tid * 8];
  const size_t rows64 = (size_t)64 * K;

  for (int k0 = 0; k0 < K; k0 += 32) {
    __syncthreads();
    gload_lds16(ga + k0, lA0);
    gload_lds16(ga + k0 + rows64, lA1);
    gload_lds16(gb + k0, lB0);
    gload_lds16(gb + k0 + rows64, lB1);
    __syncthreads();
    short8 af[4], bf[4];
#pragma unroll
    for (int mi = 0; mi < 4; mi++)
      af[mi] = *(const short8*)&As[(wm + mi * 16 + fr) * 32 + kb];
#pragma unroll
    for (int nj = 0; nj < 4; nj++)
      bf[nj] = *(const short8*)&Bs[(wn + nj * 16 + fr) * 32 + kb];
#pragma unroll
    for (int mi = 0; mi < 4; mi++)
#pragma unroll
      for (int nj = 0; nj < 4; nj++)
        acc[mi][nj] = mfma16(af[mi], bf[nj], acc[mi][nj]);
  }

  const int r0 = (lane >> 4) << 2;
  const bool isv = (MODE == 1) && (n0 >= 1536);  // whole 128-tile is one side
#pragma unroll
  for (int mi = 0; mi < 4; mi++) {
    const int row = m0 + wm + mi * 16 + r0;
#pragma unroll
    for (int nj = 0; nj < 4; nj++) {
      const int col = n0 + wn + nj * 16 + fr;
      const float bs = bias[col];
      f32x4 v = acc[mi][nj];
#pragma unroll
      for (int r = 0; r < 4; r++) {
        float val = v[r] + bs;
        int token = row + r;
        if (MODE == 0) {
          ((float*)C)[(size_t)token * N + col] = val;
        } else if (!isv) {
          ((u16*)C)[(size_t)token * 1536 + col] = f2bf(val);
        } else {
          int d = col - 1536;
          int hh = d >> 6, dd = d & 63;
          int bb = token >> 10, t = token & 1023;
          vTo[((size_t)(bb * 12 + hh) * 64 + dd) * 1024 + t] = f2bf(val);
        }
      }
    }
  }
}

// ---------------- flash attention v2 ----------------
// qk [16384][1536] bf16 (Q|K per token), vT [192][64][1024] bf16, y [16384][768] bf16.
// Block = (bh, qp): processes q-tiles qp and 15-qp (17 tile-works, balanced).
// K/V double-buffered via global_load_lds (XOR chunk swizzle), 1 barrier/tile.
__global__ __launch_bounds__(256, 3) void k_attn(const u16* __restrict__ qk,
                                                 const u16* __restrict__ vT,
                                                 const int* __restrict__ amask,
                                                 u16* __restrict__ y) {
  __shared__ __align__(16) u16 Ks[2][64 * 64];
  __shared__ __align__(16) u16 Vs[2][64 * 64];
  __shared__ __align__(16) u16 Ps[4][2][16 * 72];

  const int bh = blockIdx.x;  // 0..191  (x-major so one head's blocks share an XCD)
  const int qp = blockIdx.y;  // 0..7
  const int b = bh / 12, h = bh % 12;
  const int qbA = qp * 64, qbB = (15 - qp) * 64;
  const int nt = 16 - qp;
  const int tid = threadIdx.x, lane = tid & 63, w = tid >> 6;
  const int fr = lane & 15, kg = lane >> 4;

  const u16* qg = qk + (size_t)b * 1024 * 1536 + h * 64;
  const u16* kgp = qg + 768;
  const u16* vg = vT + (size_t)bh * 64 * 1024;
  const int* mrow = amask + b * 1024;

  // Q fragments straight from global (one-time, L2-resident)
  short8 qfA[2], qfB[2];
  {
    const u16* ra = qg + (size_t)(qbA + w * 16 + fr) * 1536 + kg * 8;
    const u16* rb = qg + (size_t)(qbB + w * 16 + fr) * 1536 + kg * 8;
    qfA[0] = *(const short8*)ra;
    qfA[1] = *(const short8*)(ra + 32);
    qfB[0] = *(const short8*)rb;
    qfB[1] = *(const short8*)(rb + 32);
  }

  const int sr0 = tid >> 3, sc = tid & 7;
  const int sr1 = sr0 + 32;
  const int sw0 = (sc ^ (sr0 & 7)) << 3;  // (sr1&7)==(sr0&7)

#define STAGE_KV(buf, kv0)                                                          \
  {                                                                                 \
    gload_lds16(kgp + (size_t)((kv0) + sr0) * 1536 + sw0, &Ks[buf][tid * 8]);       \
    gload_lds16(kgp + (size_t)((kv0) + sr1) * 1536 + sw0, &Ks[buf][2048 + tid * 8]);\
    gload_lds16(vg + (size_t)sr0 * 1024 + (kv0) + sw0, &Vs[buf][tid * 8]);          \
    gload_lds16(vg + (size_t)sr1 * 1024 + (kv0) + sw0, &Vs[buf][2048 + tid * 8]);   \
  }

  STAGE_KV(0, 0);

  f32x4 oA[4], oB[4];
  float mA[4], lA[4], mB[4], lB[4];
#pragma unroll
  for (int i = 0; i < 4; i++) {
    oA[i] = (f32x4){0.f, 0.f, 0.f, 0.f};
    oB[i] = (f32x4){0.f, 0.f, 0.f, 0.f};
    mA[i] = -1e30f; lA[i] = 0.f;
    mB[i] = -1e30f; lB[i] = 0.f;
  }
  u16* PwA = &Ps[w][0][0];
  u16* PwB = &Ps[w][1][0];

  __syncthreads();

  for (int it = 0; it < nt; ++it) {
    const int kv0 = it * 64;
    const int cur = it & 1;
    if (it + 1 < nt) STAGE_KV(cur ^ 1, kv0 + 64);
    const bool aAct = (it <= qp);
    const u16* Kc = Ks[cur];
    const u16* Vc = Vs[cur];

    // ---- QK^T for both q-tiles, K fragments shared ----
    f32x4 sA[4], sB[4];
#pragma unroll
    for (int nf = 0; nf < 4; nf++) {
      sA[nf] = (f32x4){0.f, 0.f, 0.f, 0.f};
      sB[nf] = (f32x4){0.f, 0.f, 0.f, 0.f};
    }
#pragma unroll
    for (int nf = 0; nf < 4; nf++) {
      const int base = (nf * 16 + fr) * 64;
      short8 k0 = *(const short8*)&Kc[base + ((kg ^ (fr & 7)) << 3)];
      short8 k1 = *(const short8*)&Kc[base + (((kg + 4) ^ (fr & 7)) << 3)];
      sB[nf] = mfma16(qfB[0], k0, sB[nf]);
      sB[nf] = mfma16(qfB[1], k1, sB[nf]);
      if (aAct) {
        sA[nf] = mfma16(qfA[0], k0, sA[nf]);
        sA[nf] = mfma16(qfA[1], k1, sA[nf]);
      }
    }

    // key-padding mask per column group (shared by A and B)
    float kmok[4];
#pragma unroll
    for (int nf = 0; nf < 4; nf++)
      kmok[nf] = (mrow[kv0 + nf * 16 + fr] != 0) ? 0.f : -1e9f;

    auto softmax = [&](f32x4(&s)[4], float(&mr)[4], float(&lr)[4], f32x4(&oa)[4],
                       u16* Pw, int qb, bool diag) {
#pragma unroll
      for (int nf = 0; nf < 4; nf++)
#pragma unroll
        for (int r = 0; r < 4; r++) {
          float v = s[nf][r] * 0.125f + kmok[nf];
          if (diag) {
            int kv = kv0 + nf * 16 + fr;
            int q = qb + w * 16 + kg * 4 + r;
            if (kv > q) v = -1e9f;
          }
          s[nf][r] = v;
        }
      float mnw[4];
#pragma unroll
      for (int r = 0; r < 4; r++) {
        float m = fmaxf(fmaxf(s[0][r], s[1][r]), fmaxf(s[2][r], s[3][r]));
        m = fmaxf(m, __shfl_xor(m, 1));
        m = fmaxf(m, __shfl_xor(m, 2));
        m = fmaxf(m, __shfl_xor(m, 4));
        m = fmaxf(m, __shfl_xor(m, 8));
        float mnew = fmaxf(mr[r], m);
        float alpha = __expf(mr[r] - mnew);
        mr[r] = mnew;
        mnw[r] = mnew;
        lr[r] *= alpha;
        oa[0][r] *= alpha; oa[1][r] *= alpha;
        oa[2][r] *= alpha; oa[3][r] *= alpha;
      }
      float psum[4] = {0.f, 0.f, 0.f, 0.f};
#pragma unroll
      for (int nf = 0; nf < 4; nf++)
#pragma unroll
        for (int r = 0; r < 4; r++) {
          float e = __expf(s[nf][r] - mnw[r]);
          psum[r] += e;
          Pw[(kg * 4 + r) * 72 + nf * 16 + fr] = f2bf(e);
        }
#pragma unroll
      for (int r = 0; r < 4; r++) {
        float ssum = psum[r];
        ssum += __shfl_xor(ssum, 1);
        ssum += __shfl_xor(ssum, 2);
        ssum += __shfl_xor(ssum, 4);
        ssum += __shfl_xor(ssum, 8);
        lr[r] += ssum;
      }
    };

    if (aAct) softmax(sA, mA, lA, oA, PwA, qbA, it == qp);
    softmax(sB, mB, lB, oB, PwB, qbB, it == nt - 1);

    // ---- PV for both q-tiles, V fragments shared ----
#pragma unroll
    for (int kc = 0; kc < 2; kc++) {
      short8 pB = *(const short8*)&PwB[fr * 72 + kc * 32 + kg * 8];
      short8 pA;
      if (aAct) pA = *(const short8*)&PwA[fr * 72 + kc * 32 + kg * 8];
#pragma unroll
      for (int df = 0; df < 4; df++) {
        short8 vf = *(const short8*)&Vc[(df * 16 + fr) * 64 + (((kc * 4 + kg) ^ (fr & 7)) << 3)];
        oB[df] = mfma16(pB, vf, oB[df]);
        if (aAct) oA[df] = mfma16(pA, vf, oA[df]);
      }
    }
    __syncthreads();
  }

  // epilogue: normalize, query mask, write y bf16 [token][C]
#pragma unroll
  for (int r = 0; r < 4; r++) {
    int qA = qbA + w * 16 + kg * 4 + r;
    int qB = qbB + w * 16 + kg * 4 + r;
    float nA = (mrow[qA] != 0) ? (1.f / lA[r]) : 0.f;
    float nB = (mrow[qB] != 0) ? (1.f / lB[r]) : 0.f;
#pragma unroll
    for (int df = 0; df < 4; df++) {
      y[(size_t)(b * 1024 + qA) * 768 + h * 64 + df * 16 + fr] = f2bf(oA[df][r] * nA);
      y[(size_t)(b * 1024 + qB) * 768 + h * 64 + df * 16 + fr] = f2bf(oB[df][r] * nB);
    }
  }
}

extern "C" void kernel_launch(void* const* d_in, const int* in_sizes, int n_in,
                              void* d_out, int out_size, void* d_ws, size_t ws_size,
                              hipStream_t stream) {
  const float* x = (const float*)d_in[0];
  const int* amask = (const int*)d_in[1];
  const float* W_attn = (const float*)d_in[2];
  const float* b_attn = (const float*)d_in[3];
  const float* W_proj = (const float*)d_in[4];
  const float* b_proj = (const float*)d_in[5];
  float* out = (float*)d_out;

  // workspace layout (bf16 halves), ~131 MB total
  u16* xb = (u16*)d_ws;                          // 16384*768
  u16* wta = xb + (size_t)16384 * 768;           // 2304*768
  u16* wtp = wta + (size_t)2304 * 768;           // 768*768
  u16* qk = wtp + (size_t)768 * 768;             // 16384*1536
  u16* vT = qk + (size_t)16384 * 1536;           // 192*64*1024
  u16* yb = vT + (size_t)192 * 64 * 1024;        // 16384*768

  (void)in_sizes; (void)n_in; (void)out_size; (void)ws_size;

  k_cvt<<<(16384 * 768 / 4) / 256, 256, 0, stream>>>(x, xb, 16384 * 768 / 4);
  k_transpose_cvt<<<dim3(2304 / 32, 768 / 32), 256, 0, stream>>>(W_attn, wta, 768, 2304);
  k_transpose_cvt<<<dim3(768 / 32, 768 / 32), 256, 0, stream>>>(W_proj, wtp, 768, 768);

  k_gemm<1><<<(16384 / 128) * (2304 / 128), 256, 0, stream>>>(xb, wta, b_attn, qk, vT,
                                                              16384, 2304, 768);
  k_attn<<<dim3(192, 8), 256, 0, stream>>>(qk, vT, amask, yb);
  k_gemm<0><<<(16384 / 128) * (768 / 128), 256, 0, stream>>>(yb, wtp, b_proj, out, nullptr,
                                                             16384, 768, 768);
}

// Round 4
// 236.091 us; speedup vs baseline: 1.5669x; 1.1180x over previous
//
#include <hip/hip_runtime.h>
#include <stdint.h>

typedef unsigned short u16;
typedef unsigned int u32;
typedef __attribute__((ext_vector_type(8))) short short8;
typedef __attribute__((ext_vector_type(4))) float f32x4;
typedef __attribute__((ext_vector_type(4))) unsigned short u16x4;

#define LDS_AS __attribute__((address_space(3)))
#define GLB_AS __attribute__((address_space(1)))

__device__ __forceinline__ u16 f2bf(float f) {
  u32 u = __float_as_uint(f);
  u = (u + 0x7FFFu + ((u >> 16) & 1u)) >> 16;
  return (u16)u;
}

__device__ __forceinline__ void gload_lds16(const u16* g, u16* l) {
  __builtin_amdgcn_global_load_lds((const GLB_AS u32*)g, (LDS_AS u32*)l, 16, 0, 0);
}

__device__ __forceinline__ f32x4 mfma16(short8 a, short8 b, f32x4 c) {
  return __builtin_amdgcn_mfma_f32_16x16x32_bf16(a, b, c, 0, 0, 0);
}

// ---------------- fp32 -> bf16 elementwise convert (vectorized) ----------------
__global__ __launch_bounds__(256) void k_cvt(const float* __restrict__ in,
                                             u16* __restrict__ out, int n4) {
  int i = blockIdx.x * 256 + threadIdx.x;
  if (i >= n4) return;
  f32x4 v = ((const f32x4*)in)[i];
  u16x4 o = {f2bf(v[0]), f2bf(v[1]), f2bf(v[2]), f2bf(v[3])};
  ((u16x4*)out)[i] = o;
}

// ---------------- W [K][N] f32 -> Wt [N][K] bf16 (LDS tile transpose) ----------------
__global__ __launch_bounds__(256) void k_transpose_cvt(const float* __restrict__ W,
                                                       u16* __restrict__ Wt, int K, int N) {
  __shared__ float tile[32][33];
  int n0 = blockIdx.x * 32;
  int k0 = blockIdx.y * 32;
  int tx = threadIdx.x & 31, ty = threadIdx.x >> 5;  // ty 0..7
#pragma unroll
  for (int i = 0; i < 4; i++) {
    int k = k0 + ty + i * 8;
    tile[ty + i * 8][tx] = W[(size_t)k * N + n0 + tx];
  }
  __syncthreads();
#pragma unroll
  for (int i = 0; i < 4; i++) {
    int n = n0 + ty + i * 8;
    Wt[(size_t)n * K + k0 + tx] = f2bf(tile[tx][ty + i * 8]);
  }
}

// ---------------- bf16 GEMM v2: C = A[M][K] * Bt[N][K]^T + bias ----------------
// 128x128 tile, BK=64, double-buffered LDS, counted vmcnt(8), raw barriers,
// XOR chunk swizzle (T2) on LDS tiles.
// MODE 0: fp32 C[M][N].  MODE 1: qkv split -> qk bf16 [M][1536] (cols<1536) and
// vT bf16 [B*H][64][1024] (cols>=1536, transposed per head).
template <int MODE>
__global__ __launch_bounds__(256) void k_gemm(const u16* __restrict__ A,
                                              const u16* __restrict__ Bt,
                                              const float* __restrict__ bias,
                                              void* __restrict__ C, u16* __restrict__ vTo,
                                              int M, int N, int K) {
  __shared__ __align__(16) u16 As[2][128 * 64];
  __shared__ __align__(16) u16 Bs[2][128 * 64];
  const int nwg = gridDim.x;
  const int wgo = blockIdx.x;
  const int cpx = nwg >> 3;  // grids are multiples of 8
  const int swz = (wgo & 7) * cpx + (wgo >> 3);
  const int ntn = N >> 7;
  const int tm = swz / ntn, tn = swz % ntn;
  const int m0 = tm << 7, n0 = tn << 7;
  const int tid = threadIdx.x;
  const int lane = tid & 63, w = tid >> 6;
  const int wm = (w >> 1) << 6, wn = (w & 1) << 6;
  const int fr = lane & 15, kg = lane >> 4;

  f32x4 acc[4][4];
#pragma unroll
  for (int i = 0; i < 4; i++)
#pragma unroll
    for (int j = 0; j < 4; j++) acc[i][j] = (f32x4){0.f, 0.f, 0.f, 0.f};

  // staging geometry: per STAGE-call s (0..3): row = s*32 + (tid>>3), 16B chunk = tid&7,
  // LDS linear = s*4KB + tid*16B; global column chunk = (tid&7) ^ (row&7)  [T2 inverse swz]
  const int rs = tid >> 3;
  const int ck = (((tid & 7) ^ (rs & 7)) << 3);  // u16 units
  const u16* ga = A + (size_t)(m0 + rs) * K + ck;
  const u16* gb = Bt + (size_t)(n0 + rs) * K + ck;
  const size_t row32 = (size_t)32 * K;

#define GSTAGE(buf, kt)                                                      \
  {                                                                          \
    const int ko = (kt) * 64;                                                \
    _Pragma("unroll") for (int s = 0; s < 4; ++s) {                          \
      gload_lds16(ga + s * row32 + ko, &As[buf][s * 2048 + tid * 8]);        \
    }                                                                        \
    _Pragma("unroll") for (int s = 0; s < 4; ++s) {                          \
      gload_lds16(gb + s * row32 + ko, &Bs[buf][s * 2048 + tid * 8]);        \
    }                                                                        \
  }

  const int KT = K >> 6;
  GSTAGE(0, 0);

  for (int kt = 0; kt < KT; ++kt) {
    const int cur = kt & 1;
    if (kt + 1 < KT) {
      GSTAGE(cur ^ 1, kt + 1);
      asm volatile("s_waitcnt vmcnt(8)" ::: "memory");  // own tile-kt loads landed
    } else {
      asm volatile("s_waitcnt vmcnt(0)" ::: "memory");
    }
    __builtin_amdgcn_sched_barrier(0);
    __builtin_amdgcn_s_barrier();  // all waves' tile-kt loads landed
    __builtin_amdgcn_sched_barrier(0);

#pragma unroll
    for (int kk = 0; kk < 2; ++kk) {
      short8 af[4], bf[4];
      const int cs = ((kk * 4 + kg) ^ (fr & 7)) << 3;  // swizzled read chunk (u16)
#pragma unroll
      for (int mi = 0; mi < 4; mi++)
        af[mi] = *(const short8*)&As[cur][(wm + mi * 16 + fr) * 64 + cs];
#pragma unroll
      for (int nj = 0; nj < 4; nj++)
        bf[nj] = *(const short8*)&Bs[cur][(wn + nj * 16 + fr) * 64 + cs];
      asm volatile("s_waitcnt lgkmcnt(0)" ::: "memory");
      __builtin_amdgcn_sched_barrier(0);
#pragma unroll
      for (int mi = 0; mi < 4; mi++)
#pragma unroll
        for (int nj = 0; nj < 4; nj++)
          acc[mi][nj] = mfma16(af[mi], bf[nj], acc[mi][nj]);
    }
    __builtin_amdgcn_sched_barrier(0);
    __builtin_amdgcn_s_barrier();  // reads of buf `cur` done before it is restaged
  }
#undef GSTAGE

  const int r0 = (lane >> 4) << 2;
  const bool isv = (MODE == 1) && (n0 >= 1536);  // whole 128-tile is one side
#pragma unroll
  for (int mi = 0; mi < 4; mi++) {
    const int row = m0 + wm + mi * 16 + r0;
#pragma unroll
    for (int nj = 0; nj < 4; nj++) {
      const int col = n0 + wn + nj * 16 + fr;
      const float bs = bias[col];
      f32x4 v = acc[mi][nj];
      if (MODE == 0) {
#pragma unroll
        for (int r = 0; r < 4; r++)
          ((float*)C)[(size_t)(row + r) * N + col] = v[r] + bs;
      } else if (!isv) {
#pragma unroll
        for (int r = 0; r < 4; r++)
          ((u16*)C)[(size_t)(row + r) * 1536 + col] = f2bf(v[r] + bs);
      } else {
        int d = col - 1536;
        int hh = d >> 6, dd = d & 63;
        int bb = row >> 10, t = row & 1023;  // 4 consecutive tokens, same b
        u16x4 pk = {f2bf(v[0] + bs), f2bf(v[1] + bs), f2bf(v[2] + bs), f2bf(v[3] + bs)};
        *(u16x4*)&vTo[((size_t)(bb * 12 + hh) * 64 + dd) * 1024 + t] = pk;
      }
    }
  }
}

// ---------------- flash attention v2 (unchanged from round 3) ----------------
__global__ __launch_bounds__(256, 3) void k_attn(const u16* __restrict__ qk,
                                                 const u16* __restrict__ vT,
                                                 const int* __restrict__ amask,
                                                 u16* __restrict__ y) {
  __shared__ __align__(16) u16 Ks[2][64 * 64];
  __shared__ __align__(16) u16 Vs[2][64 * 64];
  __shared__ __align__(16) u16 Ps[4][2][16 * 72];

  const int bh = blockIdx.x;  // 0..191
  const int qp = blockIdx.y;  // 0..7
  const int b = bh / 12, h = bh % 12;
  const int qbA = qp * 64, qbB = (15 - qp) * 64;
  const int nt = 16 - qp;
  const int tid = threadIdx.x, lane = tid & 63, w = tid >> 6;
  const int fr = lane & 15, kg = lane >> 4;

  const u16* qg = qk + (size_t)b * 1024 * 1536 + h * 64;
  const u16* kgp = qg + 768;
  const u16* vg = vT + (size_t)bh * 64 * 1024;
  const int* mrow = amask + b * 1024;

  short8 qfA[2], qfB[2];
  {
    const u16* ra = qg + (size_t)(qbA + w * 16 + fr) * 1536 + kg * 8;
    const u16* rb = qg + (size_t)(qbB + w * 16 + fr) * 1536 + kg * 8;
    qfA[0] = *(const short8*)ra;
    qfA[1] = *(const short8*)(ra + 32);
    qfB[0] = *(const short8*)rb;
    qfB[1] = *(const short8*)(rb + 32);
  }

  const int sr0 = tid >> 3, sc = tid & 7;
  const int sr1 = sr0 + 32;
  const int sw0 = (sc ^ (sr0 & 7)) << 3;

#define STAGE_KV(buf, kv0)                                                          \
  {                                                                                 \
    gload_lds16(kgp + (size_t)((kv0) + sr0) * 1536 + sw0, &Ks[buf][tid * 8]);       \
    gload_lds16(kgp + (size_t)((kv0) + sr1) * 1536 + sw0, &Ks[buf][2048 + tid * 8]);\
    gload_lds16(vg + (size_t)sr0 * 1024 + (kv0) + sw0, &Vs[buf][tid * 8]);          \
    gload_lds16(vg + (size_t)sr1 * 1024 + (kv0) + sw0, &Vs[buf][2048 + tid * 8]);   \
  }

  STAGE_KV(0, 0);

  f32x4 oA[4], oB[4];
  float mA[4], lA[4], mB[4], lB[4];
#pragma unroll
  for (int i = 0; i < 4; i++) {
    oA[i] = (f32x4){0.f, 0.f, 0.f, 0.f};
    oB[i] = (f32x4){0.f, 0.f, 0.f, 0.f};
    mA[i] = -1e30f; lA[i] = 0.f;
    mB[i] = -1e30f; lB[i] = 0.f;
  }
  u16* PwA = &Ps[w][0][0];
  u16* PwB = &Ps[w][1][0];

  __syncthreads();

  for (int it = 0; it < nt; ++it) {
    const int kv0 = it * 64;
    const int cur = it & 1;
    if (it + 1 < nt) STAGE_KV(cur ^ 1, kv0 + 64);
    const bool aAct = (it <= qp);
    const u16* Kc = Ks[cur];
    const u16* Vc = Vs[cur];

    f32x4 sA[4], sB[4];
#pragma unroll
    for (int nf = 0; nf < 4; nf++) {
      sA[nf] = (f32x4){0.f, 0.f, 0.f, 0.f};
      sB[nf] = (f32x4){0.f, 0.f, 0.f, 0.f};
    }
#pragma unroll
    for (int nf = 0; nf < 4; nf++) {
      const int base = (nf * 16 + fr) * 64;
      short8 k0 = *(const short8*)&Kc[base + ((kg ^ (fr & 7)) << 3)];
      short8 k1 = *(const short8*)&Kc[base + (((kg + 4) ^ (fr & 7)) << 3)];
      sB[nf] = mfma16(qfB[0], k0, sB[nf]);
      sB[nf] = mfma16(qfB[1], k1, sB[nf]);
      if (aAct) {
        sA[nf] = mfma16(qfA[0], k0, sA[nf]);
        sA[nf] = mfma16(qfA[1], k1, sA[nf]);
      }
    }

    float kmok[4];
#pragma unroll
    for (int nf = 0; nf < 4; nf++)
      kmok[nf] = (mrow[kv0 + nf * 16 + fr] != 0) ? 0.f : -1e9f;

    auto softmax = [&](f32x4(&s)[4], float(&mr)[4], float(&lr)[4], f32x4(&oa)[4],
                       u16* Pw, int qb, bool diag) {
#pragma unroll
      for (int nf = 0; nf < 4; nf++)
#pragma unroll
        for (int r = 0; r < 4; r++) {
          float v = s[nf][r] * 0.125f + kmok[nf];
          if (diag) {
            int kv = kv0 + nf * 16 + fr;
            int q = qb + w * 16 + kg * 4 + r;
            if (kv > q) v = -1e9f;
          }
          s[nf][r] = v;
        }
      float mnw[4];
#pragma unroll
      for (int r = 0; r < 4; r++) {
        float m = fmaxf(fmaxf(s[0][r], s[1][r]), fmaxf(s[2][r], s[3][r]));
        m = fmaxf(m, __shfl_xor(m, 1));
        m = fmaxf(m, __shfl_xor(m, 2));
        m = fmaxf(m, __shfl_xor(m, 4));
        m = fmaxf(m, __shfl_xor(m, 8));
        float mnew = fmaxf(mr[r], m);
        float alpha = __expf(mr[r] - mnew);
        mr[r] = mnew;
        mnw[r] = mnew;
        lr[r] *= alpha;
        oa[0][r] *= alpha; oa[1][r] *= alpha;
        oa[2][r] *= alpha; oa[3][r] *= alpha;
      }
      float psum[4] = {0.f, 0.f, 0.f, 0.f};
#pragma unroll
      for (int nf = 0; nf < 4; nf++)
#pragma unroll
        for (int r = 0; r < 4; r++) {
          float e = __expf(s[nf][r] - mnw[r]);
          psum[r] += e;
          Pw[(kg * 4 + r) * 72 + nf * 16 + fr] = f2bf(e);
        }
#pragma unroll
      for (int r = 0; r < 4; r++) {
        float ssum = psum[r];
        ssum += __shfl_xor(ssum, 1);
        ssum += __shfl_xor(ssum, 2);
        ssum += __shfl_xor(ssum, 4);
        ssum += __shfl_xor(ssum, 8);
        lr[r] += ssum;
      }
    };

    if (aAct) softmax(sA, mA, lA, oA, PwA, qbA, it == qp);
    softmax(sB, mB, lB, oB, PwB, qbB, it == nt - 1);

#pragma unroll
    for (int kc = 0; kc < 2; kc++) {
      short8 pB = *(const short8*)&PwB[fr * 72 + kc * 32 + kg * 8];
      short8 pA;
      if (aAct) pA = *(const short8*)&PwA[fr * 72 + kc * 32 + kg * 8];
#pragma unroll
      for (int df = 0; df < 4; df++) {
        short8 vf = *(const short8*)&Vc[(df * 16 + fr) * 64 + (((kc * 4 + kg) ^ (fr & 7)) << 3)];
        oB[df] = mfma16(pB, vf, oB[df]);
        if (aAct) oA[df] = mfma16(pA, vf, oA[df]);
      }
    }
    __syncthreads();
  }

#pragma unroll
  for (int r = 0; r < 4; r++) {
    int qA = qbA + w * 16 + kg * 4 + r;
    int qB = qbB + w * 16 + kg * 4 + r;
    float nA = (mrow[qA] != 0) ? (1.f / lA[r]) : 0.f;
    float nB = (mrow[qB] != 0) ? (1.f / lB[r]) : 0.f;
#pragma unroll
    for (int df = 0; df < 4; df++) {
      y[(size_t)(b * 1024 + qA) * 768 + h * 64 + df * 16 + fr] = f2bf(oA[df][r] * nA);
      y[(size_t)(b * 1024 + qB) * 768 + h * 64 + df * 16 + fr] = f2bf(oB[df][r] * nB);
    }
  }
}

extern "C" void kernel_launch(void* const* d_in, const int* in_sizes, int n_in,
                              void* d_out, int out_size, void* d_ws, size_t ws_size,
                              hipStream_t stream) {
  const float* x = (const float*)d_in[0];
  const int* amask = (const int*)d_in[1];
  const float* W_attn = (const float*)d_in[2];
  const float* b_attn = (const float*)d_in[3];
  const float* W_proj = (const float*)d_in[4];
  const float* b_proj = (const float*)d_in[5];
  float* out = (float*)d_out;

  u16* xb = (u16*)d_ws;                          // 16384*768
  u16* wta = xb + (size_t)16384 * 768;           // 2304*768
  u16* wtp = wta + (size_t)2304 * 768;           // 768*768
  u16* qk = wtp + (size_t)768 * 768;             // 16384*1536
  u16* vT = qk + (size_t)16384 * 1536;           // 192*64*1024
  u16* yb = vT + (size_t)192 * 64 * 1024;        // 16384*768

  (void)in_sizes; (void)n_in; (void)out_size; (void)ws_size;

  k_cvt<<<(16384 * 768 / 4) / 256, 256, 0, stream>>>(x, xb, 16384 * 768 / 4);
  k_transpose_cvt<<<dim3(2304 / 32, 768 / 32), 256, 0, stream>>>(W_attn, wta, 768, 2304);
  k_transpose_cvt<<<dim3(768 / 32, 768 / 32), 256, 0, stream>>>(W_proj, wtp, 768, 768);

  k_gemm<1><<<(16384 / 128) * (2304 / 128), 256, 0, stream>>>(xb, wta, b_attn, qk, vT,
                                                              16384, 2304, 768);
  k_attn<<<dim3(192, 8), 256, 0, stream>>>(qk, vT, amask, yb);
  k_gemm<0><<<(16384 / 128) * (768 / 128), 256, 0, stream>>>(yb, wtp, b_proj, out, nullptr,
                                                             16384, 768, 768);
}